// Round 2
// baseline (248.527 us; speedup 1.0000x reference)
//
#include <hip/hip_runtime.h>
#include <hip/hip_bf16.h>

// Problem constants (see reference): EMBED = L = 2048, N = 4.
#define E   2048
#define NB  4
#define LQ  2048

// Algebraic collapse of the reference:
//   einsum("nqk,nvd->nqv", att, v) = (sum_k att[n,q,k]) * (sum_d v[n,v,d])
//                                  = 1 * S[n,v]   (softmax rows sum to 1)
//   S[n,l] = values[n,l,:].cw + sb,  cw[j] = sum_d Wv[d,j], sb = sum_d bv[d]
//   out[n,q,e] = sum_v S[n,v]*Wo[e,v] + bo[e] = t[n,e]   (broadcast over q)
// Output dtype is FLOAT32 (inputs are f32; jnp preserves f32).
//
// Workspace layout (floats):
//   cw [0 .. 2047] | sb [2048] | S [4096 .. 12287] | t [12288 .. 20479]
#define WS_CW 0
#define WS_SB 2048
#define WS_S  4096
#define WS_T  12288

// ---------------------------------------------------------------------------
// Kernel A: cw[j] = sum_d Wv[d*E + j]  (atomicAdd partials; cw/sb pre-zeroed)
//           block 512 reduces bv -> sb
// ---------------------------------------------------------------------------
__global__ void __launch_bounds__(256)
sa_colsum_kernel(const float* __restrict__ Wv, const float* __restrict__ bv,
                 float* __restrict__ ws) {
    const int b = blockIdx.x;
    const int tid = threadIdx.x;
    if (b < 512) {
        const int j  = (b & 7) * 256 + tid;
        const int d0 = (b >> 3) * 32;
        float acc = 0.f;
#pragma unroll 8
        for (int d = d0; d < d0 + 32; ++d) {
            acc += Wv[(size_t)d * E + j];
        }
        atomicAdd(&ws[WS_CW + j], acc);
    } else {
        __shared__ float red[256];
        float acc = 0.f;
        for (int i = tid; i < E; i += 256) acc += bv[i];
        red[tid] = acc;
        __syncthreads();
        for (int s = 128; s > 0; s >>= 1) {
            if (tid < s) red[tid] += red[tid + s];
            __syncthreads();
        }
        if (tid == 0) ws[WS_SB] = red[0];
    }
}

// ---------------------------------------------------------------------------
// Kernel B: S[r] = dot(values[r, :], cw) + sb     r in [0, N*L)
// one block (256 thr) per row
// ---------------------------------------------------------------------------
__global__ void __launch_bounds__(256)
sa_rowdot_kernel(const float* __restrict__ values, float* __restrict__ ws) {
    const int r   = blockIdx.x;
    const int tid = threadIdx.x;
    const float4* __restrict__ v4 = reinterpret_cast<const float4*>(values + (size_t)r * E);
    const float4* __restrict__ c4 = reinterpret_cast<const float4*>(ws + WS_CW);

    float acc = 0.f;
#pragma unroll
    for (int i = 0; i < 2; ++i) {
        float4 a = v4[i * 256 + tid];
        float4 c = c4[i * 256 + tid];
        acc += a.x * c.x + a.y * c.y + a.z * c.z + a.w * c.w;
    }
#pragma unroll
    for (int off = 32; off > 0; off >>= 1) acc += __shfl_down(acc, off, 64);
    __shared__ float wsum[4];
    if ((tid & 63) == 0) wsum[tid >> 6] = acc;
    __syncthreads();
    if (tid == 0) {
        float tot = wsum[0] + wsum[1] + wsum[2] + wsum[3];
        ws[WS_S + r] = tot + ws[WS_SB];
    }
}

// ---------------------------------------------------------------------------
// Kernel C: t[n,e] = sum_v S[n,v] * Wo[e,v] + bo[e]
// one block per output column e; all 4 n at once
// ---------------------------------------------------------------------------
__global__ void __launch_bounds__(256)
sa_gemv_kernel(const float* __restrict__ Wo, const float* __restrict__ bo,
               float* __restrict__ ws) {
    const int e   = blockIdx.x;
    const int tid = threadIdx.x;
    const float4* __restrict__ w4 = reinterpret_cast<const float4*>(Wo + (size_t)e * E);
    const float4* __restrict__ s4 = reinterpret_cast<const float4*>(ws + WS_S);

    float acc[NB] = {0.f, 0.f, 0.f, 0.f};
#pragma unroll
    for (int i = 0; i < 2; ++i) {
        float4 w = w4[i * 256 + tid];
#pragma unroll
        for (int n = 0; n < NB; ++n) {
            float4 s = s4[n * 512 + i * 256 + tid];
            acc[n] += w.x * s.x + w.y * s.y + w.z * s.z + w.w * s.w;
        }
    }
#pragma unroll
    for (int off = 32; off > 0; off >>= 1) {
#pragma unroll
        for (int n = 0; n < NB; ++n) acc[n] += __shfl_down(acc[n], off, 64);
    }
    __shared__ float wsum[4][NB];
    if ((tid & 63) == 0) {
#pragma unroll
        for (int n = 0; n < NB; ++n) wsum[tid >> 6][n] = acc[n];
    }
    __syncthreads();
    if (tid < NB) {
        float r = wsum[0][tid] + wsum[1][tid] + wsum[2][tid] + wsum[3][tid];
        ws[WS_T + tid * E + e] = r + bo[e];
    }
}

// ---------------------------------------------------------------------------
// Kernel D: out[n,q,e] = t[n,e]  (FLOAT32 broadcast over q, float4 stores)
// one float4 per thread; 16384 blocks x 256 threads
// ---------------------------------------------------------------------------
__global__ void __launch_bounds__(256)
sa_bcast_kernel(const float* __restrict__ ws, float* __restrict__ out) {
    const unsigned int gid  = blockIdx.x * 256u + threadIdx.x;
    const unsigned int base = gid * 4u;            // element index into [N, L, E]
    const unsigned int n    = base >> 22;          // L*E = 2^22
    const unsigned int e    = base & (E - 1);      // multiple of 4
    const float4* __restrict__ t4 = reinterpret_cast<const float4*>(ws + WS_T);
    float4 v = t4[(n * E + e) >> 2];
    reinterpret_cast<float4*>(out)[gid] = v;
}

// ---------------------------------------------------------------------------
extern "C" void kernel_launch(void* const* d_in, const int* in_sizes, int n_in,
                              void* d_out, int out_size, void* d_ws, size_t ws_size,
                              hipStream_t stream) {
    const float* values = (const float*)d_in[0];
    // d_in[1] keys, d_in[2] queries, d_in[5..8] Wk/bk/Wq/bq: provably unused
    const float* Wv = (const float*)d_in[3];
    const float* bv = (const float*)d_in[4];
    const float* Wo = (const float*)d_in[9];
    const float* bo = (const float*)d_in[10];
    float* out = (float*)d_out;
    float* ws = (float*)d_ws;

    // zero the atomic accumulation region (cw + sb); ws is re-poisoned every call
    hipMemsetAsync(ws, 0, (E + 1) * sizeof(float), stream);

    sa_colsum_kernel<<<513, 256, 0, stream>>>(Wv, bv, ws);
    sa_rowdot_kernel<<<NB * LQ, 256, 0, stream>>>(values, ws);
    sa_gemv_kernel<<<E, 256, 0, stream>>>(Wo, bo, ws);
    sa_bcast_kernel<<<(unsigned)(out_size / (256 * 4)), 256, 0, stream>>>(ws, out);
}